// Round 6
// baseline (214.585 us; speedup 1.0000x reference)
//
#include <hip/hip_runtime.h>
#include <hip/hip_bf16.h>
#include <math.h>

#define BB 8
#define NN 2048
#define DD 1024
#define LL 128
#define MM (BB*NN)   // 16384

typedef _Float16 half8 __attribute__((ext_vector_type(8)));
typedef _Float16 half4 __attribute__((ext_vector_type(4)));
typedef __attribute__((ext_vector_type(4))) float floatx4;

__device__ __forceinline__ void glds16(const void* g, void* l) {
    __builtin_amdgcn_global_load_lds(
        (const __attribute__((address_space(1))) unsigned int*)g,
        (__attribute__((address_space(3))) unsigned int*)l, 16, 0, 0);
}

// fast tanh: 1 - 2/(e^{2x}+1); saturates correctly for |x| large, ~1e-6 abs err
__device__ __forceinline__ float ftanh(float x) {
    float e = __expf(2.0f * x);
    return 1.0f - 2.0f * __builtin_amdgcn_rcpf(e + 1.0f);
}

// ---------------- K1: e_j -> fp16, Wk -> fp16, q = e_i @ Wq^T, zero u
__global__ __launch_bounds__(256) void prep_kernel(const float* __restrict__ e_j,
                                                   _Float16* __restrict__ eh,
                                                   const float* __restrict__ Wk,
                                                   _Float16* __restrict__ wh,
                                                   const float* __restrict__ e_i,
                                                   const float* __restrict__ Wq,
                                                   float* __restrict__ q,
                                                   float* __restrict__ u) {
    __shared__ float us[BB][DD];   // 32 KB, used only by the q branch
    int blk = blockIdx.x;
    int tid = threadIdx.x;
    if (blk < 8192) {
        int i = blk * 256 + tid;
        const float4* xp = (const float4*)e_j + (size_t)i * 2;
        float4 v0 = xp[0], v1 = xp[1];
        half8 h;
        h[0] = (_Float16)v0.x; h[1] = (_Float16)v0.y;
        h[2] = (_Float16)v0.z; h[3] = (_Float16)v0.w;
        h[4] = (_Float16)v1.x; h[5] = (_Float16)v1.y;
        h[6] = (_Float16)v1.z; h[7] = (_Float16)v1.w;
        *(half8*)(eh + (size_t)i * 8) = h;
    } else if (blk < 8704) {
        int i = (blk - 8192) * 256 + tid;
        const float4* xp = (const float4*)Wk + (size_t)i * 2;
        float4 v0 = xp[0], v1 = xp[1];
        half8 h;
        h[0] = (_Float16)v0.x; h[1] = (_Float16)v0.y;
        h[2] = (_Float16)v0.z; h[3] = (_Float16)v0.w;
        h[4] = (_Float16)v1.x; h[5] = (_Float16)v1.y;
        h[6] = (_Float16)v1.z; h[7] = (_Float16)v1.w;
        *(half8*)(wh + (size_t)i * 8) = h;
    } else if (blk < 8960) {
        for (int i = tid; i < BB * DD / 4; i += 256)
            ((float4*)&us[0][0])[i] = ((const float4*)e_i)[i];
        __syncthreads();
        int w = tid >> 6, lane = tid & 63;
        int d = (blk - 8704) * 4 + w;
        float acc[8] = {0.f, 0.f, 0.f, 0.f, 0.f, 0.f, 0.f, 0.f};
        for (int e0 = 0; e0 < DD; e0 += 256) {
            float4 wv = *(const float4*)&Wq[(size_t)d * DD + e0 + lane * 4];
            #pragma unroll
            for (int r = 0; r < 8; ++r) {
                float4 uv = *(const float4*)&us[r][e0 + lane * 4];
                acc[r] += wv.x * uv.x + wv.y * uv.y + wv.z * uv.z + wv.w * uv.w;
            }
        }
        #pragma unroll
        for (int r = 0; r < 8; ++r) {
            float s = acc[r];
            #pragma unroll
            for (int off = 32; off; off >>= 1) s += __shfl_down(s, off, 64);
            if (lane == 0) q[r * DD + d] = s;
        }
    } else {
        u[(blk - 8960) * 256 + tid] = 0.f;   // 32 blocks x 256 = 8192
    }
}

// ---------------- K2: sigma. m201 8-phase skeleton, MFMA SHIFTED one phase after
// its ds_reads so every read batch overlaps a 16-MFMA cluster.
// Reads:  ph1:F1(a03,bl)[12]  ph2:F2(bh)[4]  ph3:F3(a47)[8]  ph4:-   (x2 slots)
// MFMA:   ph1:M4(prev)        ph2:M1         ph3:M2          ph4:M3
// lgkm:   skip                4              8               0
// Stages (target's last read barrier-certified): ph1/ph2: A(k1->s1);
// ph4: B0(k2->s0); ph5: B1(k2->s0)+A0(k2->s0); ph6: A1(k2->s0); ph8: B(k3->s1)x2.
// vmcnt gates: ph4 -> 2 (certifies A+B of tile k1 for ph5 reads),
//              ph8 -> 4 (certifies tile k2 for next-ph1 reads).
__global__ __launch_bounds__(512, 2) void sigma256(const _Float16* __restrict__ eh,
                                                   const _Float16* __restrict__ wh,
                                                   const float* __restrict__ q,
                                                   const float* __restrict__ omega,
                                                   float* __restrict__ sig_part) // [4][MM]
{
    __shared__ _Float16 As[2][2][128][64];   // [slot][half] 64 KB
    __shared__ _Float16 Bs[2][2][128][64];   // 64 KB

    const int tid  = threadIdx.x;
    const int lane = tid & 63;
    const int wid  = tid >> 6;          // 0..7
    const int wm   = wid >> 2;          // 0..1 : A 128-row block
    const int wn   = wid & 3;           // 0..3 : 64-col block
    const int c15  = lane & 15, quad = lane >> 4;

    // XCD-chunked bijective swizzle: 256 wgs, 32 per XCD
    const int wgid   = (blockIdx.x & 7) * 32 + (blockIdx.x >> 3);
    const int colBlk = wgid >> 6;        // 0..3
    const int rowBlk = wgid & 63;        // 0..63
    const int row0   = rowBlk * 256;
    const int col0   = colBlk * 256;
    const int b      = row0 / NN;

    // staging: linear LDS dest, 8-way XOR swizzle folded into global source
    const int l3  = lane >> 3;
    const int qst = ((lane & 7) ^ l3) * 8;     // halfs
    const _Float16* gA = eh + (size_t)(row0 + wid * 16 + l3) * DD + qst;
    const _Float16* gB = wh + (size_t)(col0 + wid * 16 + l3) * DD + qst;
    char* const ldsA = (char*)&As[0][0][0][0] + wid * 2048;
    char* const ldsB = (char*)&Bs[0][0][0][0] + wid * 2048;

#define STG_A(kt, hf, s) do { \
    glds16(gA + (size_t)(hf) * 128 * DD + (kt) * 64,          ldsA + (s) * 32768 + (hf) * 16384); \
    glds16(gA + (size_t)(hf) * 128 * DD + (kt) * 64 + 8 * DD, ldsA + (s) * 32768 + (hf) * 16384 + 1024); } while (0)
#define STG_B(kt, hf, s) do { \
    glds16(gB + (size_t)(hf) * 128 * DD + (kt) * 64,          ldsB + (s) * 32768 + (hf) * 16384); \
    glds16(gB + (size_t)(hf) * 128 * DD + (kt) * 64 + 8 * DD, ldsB + (s) * 32768 + (hf) * 16384 + 1024); } while (0)
#define STG_P5(k2) do { STG_B(k2, 1, 0); STG_A(k2, 0, 0); } while (0)
#define STG_P8(k3) do { STG_B(k3, 0, 1); STG_B(k3, 1, 1); } while (0)

    // swizzled fragment reads: row stride 128B, q' = q ^ (row&7)
    const int swz = c15 & 7;
    const int q0  = (quad ^ swz) << 4;
    const int q1  = ((4 + quad) ^ swz) << 4;
    const char* const afp = (const char*)&As[0][0][0][0] + wm * 16384 + c15 * 128;
    const char* const bfp = (const char*)&Bs[0][0][0][0] + (wn >> 1) * 16384
                            + ((wn & 1) * 64 + c15) * 128;
#define FA(s, m, ks) (*(const half8*)(afp + (s) * 32768 + (m) * 2048 + ((ks) ? q1 : q0)))
#define FB(s, n, ks) (*(const half8*)(bfp + (s) * 32768 + (n) * 2048 + ((ks) ? q1 : q0)))

    floatx4 acc[8][4];
    #pragma unroll
    for (int m = 0; m < 8; ++m)
        #pragma unroll
        for (int n = 0; n < 4; ++n) acc[m][n] = (floatx4){0.f, 0.f, 0.f, 0.f};

    half8 a1[8], a2[8], bl[4], bh[4];

#define BARx()  __builtin_amdgcn_s_barrier()
#define SBARx() __builtin_amdgcn_sched_barrier(0)
#define WT4  asm volatile("s_waitcnt lgkmcnt(4)" ::: "memory")
#define WT8  asm volatile("s_waitcnt lgkmcnt(8)" ::: "memory")
#define WT0  asm volatile("s_waitcnt lgkmcnt(0)" ::: "memory")
#define VMC2 asm volatile("s_waitcnt vmcnt(2)" ::: "memory")
#define VMC4 asm volatile("s_waitcnt vmcnt(4)" ::: "memory")
#define VMC0 asm volatile("s_waitcnt vmcnt(0)" ::: "memory")
#define NOPX ((void)0)

#define RD_F1(s) \
    _Pragma("unroll") for (int m_ = 0; m_ < 4; ++m_) { a1[m_*2] = FA(s, m_, 0); a1[m_*2+1] = FA(s, m_, 1); } \
    _Pragma("unroll") for (int n_ = 0; n_ < 2; ++n_) { bl[n_*2] = FB(s, n_, 0); bl[n_*2+1] = FB(s, n_, 1); }
#define RD_F2(s) \
    _Pragma("unroll") for (int n_ = 0; n_ < 2; ++n_) { bh[n_*2] = FB(s, 2+n_, 0); bh[n_*2+1] = FB(s, 2+n_, 1); }
#define RD_F3(s) \
    _Pragma("unroll") for (int m_ = 0; m_ < 4; ++m_) { a2[m_*2] = FA(s, 4+m_, 0); a2[m_*2+1] = FA(s, 4+m_, 1); }

#define MFM(AR, BR, MB, NB) do { \
    __builtin_amdgcn_s_setprio(1); \
    _Pragma("unroll") for (int m_ = 0; m_ < 4; ++m_) \
    _Pragma("unroll") for (int n_ = 0; n_ < 2; ++n_) \
    _Pragma("unroll") for (int ks_ = 0; ks_ < 2; ++ks_) \
        acc[(MB)+m_][(NB)+n_] = __builtin_amdgcn_mfma_f32_16x16x32_f16( \
            AR[m_*2+ks_], BR[n_*2+ks_], acc[(MB)+m_][(NB)+n_], 0, 0, 0); \
    __builtin_amdgcn_s_setprio(0); } while (0)

#define PHASE(RD, ST, WT, MM_, VM) do { RD; ST; SBARx(); BARx(); WT; SBARx(); MM_; VM; BARx(); } while (0)

    // prologue: tile0 (s0) full + tile1 (s1) B halves = 12 insts; vmcnt(4) => tile0 landed
    STG_A(0, 0, 0); STG_A(0, 1, 0); STG_B(0, 0, 0); STG_B(0, 1, 0);
    STG_B(1, 0, 1); STG_B(1, 1, 1);
    VMC4;
    BARx();

    // iter 0 (k1=1,k2=2,k3=3): ph1 has no MFMA yet
    PHASE(RD_F1(0), STG_A(1, 0, 1), NOPX, NOPX,              NOPX);
    PHASE(RD_F2(0), STG_A(1, 1, 1), WT4,  MFM(a1, bl, 0, 0), NOPX);
    PHASE(RD_F3(0), NOPX,           WT8,  MFM(a1, bh, 0, 2), NOPX);
    PHASE(NOPX,     STG_B(2, 0, 0), WT0,  MFM(a2, bl, 4, 0), VMC2);
    PHASE(RD_F1(1), STG_P5(2),      NOPX, MFM(a2, bh, 4, 2), NOPX);
    PHASE(RD_F2(1), STG_A(2, 1, 0), WT4,  MFM(a1, bl, 0, 0), NOPX);
    PHASE(RD_F3(1), NOPX,           WT8,  MFM(a1, bh, 0, 2), NOPX);
    PHASE(NOPX,     STG_P8(3),      WT0,  MFM(a2, bl, 4, 0), VMC4);

    for (int i = 1; i < 7; ++i) {
        const int k1 = 2 * i + 1, k2 = 2 * i + 2, k3 = 2 * i + 3;
        PHASE(RD_F1(0), STG_A(k1, 0, 1), NOPX, MFM(a2, bh, 4, 2), NOPX);
        PHASE(RD_F2(0), STG_A(k1, 1, 1), WT4,  MFM(a1, bl, 0, 0), NOPX);
        PHASE(RD_F3(0), NOPX,            WT8,  MFM(a1, bh, 0, 2), NOPX);
        PHASE(NOPX,     STG_B(k2, 0, 0), WT0,  MFM(a2, bl, 4, 0), VMC2);
        PHASE(RD_F1(1), STG_P5(k2),      NOPX, MFM(a2, bh, 4, 2), NOPX);
        PHASE(RD_F2(1), STG_A(k2, 1, 0), WT4,  MFM(a1, bl, 0, 0), NOPX);
        PHASE(RD_F3(1), NOPX,            WT8,  MFM(a1, bh, 0, 2), NOPX);
        PHASE(NOPX,     STG_P8(k3),      WT0,  MFM(a2, bl, 4, 0), VMC4);
    }

    // tail iter (k1=15; tiles 14,15)
    PHASE(RD_F1(0), STG_A(15, 0, 1), NOPX, MFM(a2, bh, 4, 2), NOPX);
    PHASE(RD_F2(0), STG_A(15, 1, 1), WT4,  MFM(a1, bl, 0, 0), NOPX);
    PHASE(RD_F3(0), NOPX,            WT8,  MFM(a1, bh, 0, 2), NOPX);
    PHASE(NOPX,     NOPX,            WT0,  MFM(a2, bl, 4, 0), VMC0);
    PHASE(RD_F1(1), NOPX,            NOPX, MFM(a2, bh, 4, 2), NOPX);
    PHASE(RD_F2(1), NOPX,            WT4,  MFM(a1, bl, 0, 0), NOPX);
    PHASE(RD_F3(1), NOPX,            WT8,  MFM(a1, bh, 0, 2), NOPX);
    PHASE(NOPX,     NOPX,            WT0,  MFM(a2, bl, 4, 0), NOPX);
    MFM(a2, bh, 4, 2);   // final M4; operands certified by tail-ph8 lgkm0

#undef PHASE
#undef MFM
#undef RD_F1
#undef RD_F2
#undef RD_F3
#undef FA
#undef FB
#undef STG_A
#undef STG_B
#undef STG_P5
#undef STG_P8

    // ---- fused epilogue: part[row] = sum_cols tanh(acc+q)*omega (this wave's 64 cols)
    float part[8][4];
    #pragma unroll
    for (int m = 0; m < 8; ++m)
        #pragma unroll
        for (int r = 0; r < 4; ++r) part[m][r] = 0.f;

    #pragma unroll
    for (int n = 0; n < 4; ++n) {
        int col = col0 + wn * 64 + n * 16 + c15;
        float qv = q[b * DD + col];
        float om = omega[col];
        #pragma unroll
        for (int m = 0; m < 8; ++m)
            #pragma unroll
            for (int r = 0; r < 4; ++r)
                part[m][r] += ftanh(acc[m][n][r] + qv) * om;
    }

    float (*red)[4] = (float(*)[4])&As[0][0][0][0];   // [256][4] = 4 KB, As is dead
    #pragma unroll
    for (int m = 0; m < 8; ++m)
        #pragma unroll
        for (int r = 0; r < 4; ++r) {
            float s = part[m][r];
            s += __shfl_xor(s, 1, 64);
            s += __shfl_xor(s, 2, 64);
            s += __shfl_xor(s, 4, 64);
            s += __shfl_xor(s, 8, 64);
            if (c15 == 0) red[wm * 128 + m * 16 + quad * 4 + r][wn] = s;
        }
    __syncthreads();
    if (tid < 256)
        sig_part[(size_t)colBlk * MM + row0 + tid] =
            red[tid][0] + red[tid][1] + red[tid][2] + red[tid][3];
}

// ---------------- K3: fused softmax + u accumulation (atomic, u pre-zeroed by K1).
// Each of 1024 blocks (b,nc) recomputes b's softmax stats from the L2-resident
// sig_part (32 KB), then accumulates its 16 rows' a_ij * eh into u[b,:].
__global__ __launch_bounds__(256) void su_kernel(const float* __restrict__ sig_part,
                                                 const float* __restrict__ imp,
                                                 const _Float16* __restrict__ eh,
                                                 float* __restrict__ u) {
    int b = blockIdx.x >> 7, nc = blockIdx.x & 127;
    int tid = threadIdx.x;
    __shared__ float red[256];
    __shared__ float a_s[16];
    float m = -1e30f, sum;
    float svv[8];
    #pragma unroll
    for (int p = 0; p < 8; ++p) {
        int n = p * 256 + tid;
        float s = 0.f;
        #pragma unroll
        for (int db = 0; db < 4; ++db) s += sig_part[db * MM + b * NN + n];
        svv[p] = s;
        m = fmaxf(m, s);
    }
    red[tid] = m; __syncthreads();
    for (int off = 128; off; off >>= 1) {
        if (tid < off) red[tid] = fmaxf(red[tid], red[tid + off]);
        __syncthreads();
    }
    m = red[0]; __syncthreads();
    sum = 0.f;
    #pragma unroll
    for (int p = 0; p < 8; ++p) sum += expf(svv[p] - m);
    red[tid] = sum; __syncthreads();
    for (int off = 128; off; off >>= 1) {
        if (tid < off) red[tid] += red[tid + off];
        __syncthreads();
    }
    float inv = 1.f / (red[0] + 1e-9f * expf(-m));
    if (tid < 16) {
        int n = nc * 16 + tid;
        float s = 0.f;
        #pragma unroll
        for (int db = 0; db < 4; ++db) s += sig_part[db * MM + b * NN + n];
        a_s[tid] = imp[b * NN + n] * expf(s - m) * inv;
    }
    __syncthreads();
    float4 acc = {0.f, 0.f, 0.f, 0.f};
    const _Float16* base = eh + ((size_t)(b * NN + nc * 16)) * DD + tid * 4;
    #pragma unroll
    for (int n = 0; n < 16; ++n) {
        float a = a_s[n];
        half4 v = *(const half4*)(base + (size_t)n * DD);
        acc.x += a * (float)v[0]; acc.y += a * (float)v[1];
        acc.z += a * (float)v[2]; acc.w += a * (float)v[3];
    }
    float* up = u + (size_t)b * DD + tid * 4;
    atomicAdd(up + 0, acc.x);
    atomicAdd(up + 1, acc.y);
    atomicAdd(up + 2, acc.z);
    atomicAdd(up + 3, acc.w);
}

// ---------------- K4: fused A = u @ Wv^T + all three outputs.
// 128 blocks; block k owns d = k*8 .. k*8+7. u staged in LDS; Wv read once.
__global__ __launch_bounds__(256) void fin_kernel(const float* __restrict__ u,
                                                  const float* __restrict__ Wv,
                                                  const float* __restrict__ Rlk,
                                                  float* __restrict__ out) {
    __shared__ float us[BB][DD];   // 32 KB
    __shared__ float As[BB][8];
    int tid = threadIdx.x;
    for (int i = tid; i < BB * DD / 4; i += 256)
        ((float4*)&us[0][0])[i] = ((const float4*)u)[i];
    __syncthreads();
    int w = tid >> 6, lane = tid & 63;
    #pragma unroll
    for (int dd = 0; dd < 2; ++dd) {
        int dl = w * 2 + dd;
        int d = blockIdx.x * 8 + dl;
        float acc[8] = {0.f, 0.f, 0.f, 0.f, 0.f, 0.f, 0.f, 0.f};
        for (int e0 = 0; e0 < DD; e0 += 256) {
            float4 wv = *(const float4*)&Wv[(size_t)d * DD + e0 + lane * 4];
            #pragma unroll
            for (int r = 0; r < 8; ++r) {
                float4 uv = *(const float4*)&us[r][e0 + lane * 4];
                acc[r] += wv.x * uv.x + wv.y * uv.y + wv.z * uv.z + wv.w * uv.w;
            }
        }
        #pragma unroll
        for (int r = 0; r < 8; ++r) {
            float s = acc[r];
            #pragma unroll
            for (int off = 32; off; off >>= 1) s += __shfl_down(s, off, 64);
            if (lane == 0) {
                As[r][dl] = s;
                out[r * DD + d] = s;                               // A
                out[BB * DD + BB * LL * DD + r * DD + d] = s;      // A_l
            }
        }
    }
    __syncthreads();
    // A_lk: out[BB*DD + b*LL*DD + l*DD + k*8 .. +7] = A[b][.] * R[l][.]
    int k8 = blockIdx.x * 8;
    for (int c = tid; c < BB * LL; c += 256) {
        int bb = c >> 7, l = c & 127;
        float4 r0 = *(const float4*)&Rlk[(size_t)l * DD + k8];
        float4 r1 = *(const float4*)&Rlk[(size_t)l * DD + k8 + 4];
        float4 o0, o1;
        o0.x = As[bb][0] * r0.x; o0.y = As[bb][1] * r0.y;
        o0.z = As[bb][2] * r0.z; o0.w = As[bb][3] * r0.w;
        o1.x = As[bb][4] * r1.x; o1.y = As[bb][5] * r1.y;
        o1.z = As[bb][6] * r1.z; o1.w = As[bb][7] * r1.w;
        size_t o = (size_t)BB * DD + (size_t)bb * LL * DD + (size_t)l * DD + k8;
        *(float4*)&out[o]     = o0;
        *(float4*)&out[o + 4] = o1;
    }
}

extern "C" void kernel_launch(void* const* d_in, const int* in_sizes, int n_in,
                              void* d_out, int out_size, void* d_ws, size_t ws_size,
                              hipStream_t stream) {
    const float* e_i   = (const float*)d_in[0];
    const float* e_j   = (const float*)d_in[1];
    const float* imp   = (const float*)d_in[2];
    const float* Rlk   = (const float*)d_in[3];
    const float* Wq    = (const float*)d_in[4];
    const float* Wk    = (const float*)d_in[5];
    const float* Wv    = (const float*)d_in[6];
    const float* omega = (const float*)d_in[7];
    float* out = (float*)d_out;
    float* ws  = (float*)d_ws;

    float* q    = ws;               // 8192
    float* sigp = ws + 8192;        // 65536 used
    float* u    = ws + 155648;      // 8192
    _Float16* eh = (_Float16*)(ws + 172032);      // MM*DD halfs = 32 MB
    _Float16* wh = eh + (size_t)MM * DD;          // 2 MB

    // K1: convert + q + zero u
    prep_kernel<<<8992, 256, 0, stream>>>(e_j, eh, Wk, wh, e_i, Wq, q, u);

    // K2: sigma partials, shifted-MFMA 8-phase pipeline
    sigma256<<<dim3(256), 512, 0, stream>>>(eh, wh, q, omega, sigp);

    // K3: softmax + u accumulation (atomics)
    su_kernel<<<1024, 256, 0, stream>>>(sigp, imp, eh, u);

    // K4: A = u @ Wv^T + outputs
    fin_kernel<<<128, 256, 0, stream>>>(u, Wv, Rlk, out);
}

// Round 7
// 186.004 us; speedup vs baseline: 1.1537x; 1.1537x over previous
//
#include <hip/hip_runtime.h>
#include <hip/hip_bf16.h>
#include <math.h>

#define BB 8
#define NN 2048
#define DD 1024
#define LL 128
#define MM (BB*NN)   // 16384

typedef _Float16 half8 __attribute__((ext_vector_type(8)));
typedef _Float16 half4 __attribute__((ext_vector_type(4)));
typedef __attribute__((ext_vector_type(4))) float floatx4;

__device__ __forceinline__ void glds16(const void* g, void* l) {
    __builtin_amdgcn_global_load_lds(
        (const __attribute__((address_space(1))) unsigned int*)g,
        (__attribute__((address_space(3))) unsigned int*)l, 16, 0, 0);
}

// fast tanh: 1 - 2/(e^{2x}+1); saturates correctly for |x| large, ~1e-6 abs err
__device__ __forceinline__ float ftanh(float x) {
    float e = __expf(2.0f * x);
    return 1.0f - 2.0f * __builtin_amdgcn_rcpf(e + 1.0f);
}

// ---------------- K1: e_j -> fp16, Wk -> fp16, q = e_i @ Wq^T
__global__ __launch_bounds__(256) void prep_kernel(const float* __restrict__ e_j,
                                                   _Float16* __restrict__ eh,
                                                   const float* __restrict__ Wk,
                                                   _Float16* __restrict__ wh,
                                                   const float* __restrict__ e_i,
                                                   const float* __restrict__ Wq,
                                                   float* __restrict__ q) {
    __shared__ float us[BB][DD];   // 32 KB, used only by the q branch
    int blk = blockIdx.x;
    int tid = threadIdx.x;
    if (blk < 8192) {
        int i = blk * 256 + tid;
        const float4* xp = (const float4*)e_j + (size_t)i * 2;
        float4 v0 = xp[0], v1 = xp[1];
        half8 h;
        h[0] = (_Float16)v0.x; h[1] = (_Float16)v0.y;
        h[2] = (_Float16)v0.z; h[3] = (_Float16)v0.w;
        h[4] = (_Float16)v1.x; h[5] = (_Float16)v1.y;
        h[6] = (_Float16)v1.z; h[7] = (_Float16)v1.w;
        *(half8*)(eh + (size_t)i * 8) = h;
    } else if (blk < 8704) {
        int i = (blk - 8192) * 256 + tid;
        const float4* xp = (const float4*)Wk + (size_t)i * 2;
        float4 v0 = xp[0], v1 = xp[1];
        half8 h;
        h[0] = (_Float16)v0.x; h[1] = (_Float16)v0.y;
        h[2] = (_Float16)v0.z; h[3] = (_Float16)v0.w;
        h[4] = (_Float16)v1.x; h[5] = (_Float16)v1.y;
        h[6] = (_Float16)v1.z; h[7] = (_Float16)v1.w;
        *(half8*)(wh + (size_t)i * 8) = h;
    } else {
        for (int i = tid; i < BB * DD / 4; i += 256)
            ((float4*)&us[0][0])[i] = ((const float4*)e_i)[i];
        __syncthreads();
        int w = tid >> 6, lane = tid & 63;
        int d = (blk - 8704) * 4 + w;
        float acc[8] = {0.f, 0.f, 0.f, 0.f, 0.f, 0.f, 0.f, 0.f};
        for (int e0 = 0; e0 < DD; e0 += 256) {
            float4 wv = *(const float4*)&Wq[(size_t)d * DD + e0 + lane * 4];
            #pragma unroll
            for (int r = 0; r < 8; ++r) {
                float4 uv = *(const float4*)&us[r][e0 + lane * 4];
                acc[r] += wv.x * uv.x + wv.y * uv.y + wv.z * uv.z + wv.w * uv.w;
            }
        }
        #pragma unroll
        for (int r = 0; r < 8; ++r) {
            float s = acc[r];
            #pragma unroll
            for (int off = 32; off; off >>= 1) s += __shfl_down(s, off, 64);
            if (lane == 0) q[r * DD + d] = s;
        }
    }
}

// ---------------- K2: sigma. R4's m201 8-phase skeleton (same-phase read->MFMA,
// proven 41.8us), with CLOSING barriers removed on phases 1-3,5-7.
// Only the vmcnt-certifying fences at phases 4/8 keep their closing barrier.
// This lets waves slip <=1 phase so one wave's ds_read burst overlaps its
// SIMD-sibling's MFMA cluster (de-phasing the read/MFMA lockstep).
// Hazard audit: no stage targets a region read in the immediately preceding
// phase (min read->overwrite gap = 2 phases = >=2 opening barriers); per-wave
// lgkm0 before each MFMA unchanged; vmcnt ledger identical to R4:
//   ph4 VMC4: outstanding = A(k1)x4 + B(k2)x4 -> certifies A(k1->s1) for ph5-7
//   ph8 VMC4: outstanding = A(k2)x4 + B(k3)x4 -> certifies A(k2->s0) for next ph1-3
//   B(k->s) stages are certified by the NEXT ph4/ph8 fence before s is read.
__global__ __launch_bounds__(512, 2) void sigma256(const _Float16* __restrict__ eh,
                                                   const _Float16* __restrict__ wh,
                                                   const float* __restrict__ q,
                                                   const float* __restrict__ omega,
                                                   float* __restrict__ sig_part) // [4][MM]
{
    __shared__ _Float16 As[2][2][128][64];   // [slot][half] 64 KB
    __shared__ _Float16 Bs[2][2][128][64];   // 64 KB

    const int tid  = threadIdx.x;
    const int lane = tid & 63;
    const int wid  = tid >> 6;          // 0..7
    const int wm   = wid >> 2;          // 0..1 : A 128-row block
    const int wn   = wid & 3;           // 0..3 : 64-col block
    const int c15  = lane & 15, quad = lane >> 4;

    // XCD-chunked bijective swizzle: 256 wgs, 32 per XCD
    const int wgid   = (blockIdx.x & 7) * 32 + (blockIdx.x >> 3);
    const int colBlk = wgid >> 6;        // 0..3
    const int rowBlk = wgid & 63;        // 0..63
    const int row0   = rowBlk * 256;
    const int col0   = colBlk * 256;
    const int b      = row0 / NN;

    // staging: linear LDS dest, 8-way XOR swizzle folded into global source
    const int l3  = lane >> 3;
    const int qst = ((lane & 7) ^ l3) * 8;     // halfs
    const _Float16* gA = eh + (size_t)(row0 + wid * 16 + l3) * DD + qst;
    const _Float16* gB = wh + (size_t)(col0 + wid * 16 + l3) * DD + qst;
    char* const ldsA = (char*)&As[0][0][0][0] + wid * 2048;
    char* const ldsB = (char*)&Bs[0][0][0][0] + wid * 2048;

#define STG_A(kt, hf, s) do { \
    glds16(gA + (size_t)(hf) * 128 * DD + (kt) * 64,          ldsA + (s) * 32768 + (hf) * 16384); \
    glds16(gA + (size_t)(hf) * 128 * DD + (kt) * 64 + 8 * DD, ldsA + (s) * 32768 + (hf) * 16384 + 1024); } while (0)
#define STG_B(kt, hf, s) do { \
    glds16(gB + (size_t)(hf) * 128 * DD + (kt) * 64,          ldsB + (s) * 32768 + (hf) * 16384); \
    glds16(gB + (size_t)(hf) * 128 * DD + (kt) * 64 + 8 * DD, ldsB + (s) * 32768 + (hf) * 16384 + 1024); } while (0)

    // swizzled fragment reads: row stride 128B, q' = q ^ (row&7)
    const int swz = c15 & 7;
    const int q0  = (quad ^ swz) << 4;
    const int q1  = ((4 + quad) ^ swz) << 4;
    const char* const afp = (const char*)&As[0][0][0][0] + wm * 16384 + c15 * 128;
    const char* const bfp = (const char*)&Bs[0][0][0][0] + (wn >> 1) * 16384
                            + ((wn & 1) * 64 + c15) * 128;
#define FA(s, m, ks) (*(const half8*)(afp + (s) * 32768 + (m) * 2048 + ((ks) ? q1 : q0)))
#define FB(s, n, ks) (*(const half8*)(bfp + (s) * 32768 + (n) * 2048 + ((ks) ? q1 : q0)))

    floatx4 acc[8][4];
    #pragma unroll
    for (int m = 0; m < 8; ++m)
        #pragma unroll
        for (int n = 0; n < 4; ++n) acc[m][n] = (floatx4){0.f, 0.f, 0.f, 0.f};

    half8 a[8], bl[4], bh[4];

#define BARx()  __builtin_amdgcn_s_barrier()
#define SBARx() __builtin_amdgcn_sched_barrier(0)
#define LGKM0() asm volatile("s_waitcnt lgkmcnt(0)" ::: "memory")
#define MFMA16(MB, NB, BARR) \
    __builtin_amdgcn_s_setprio(1); \
    _Pragma("unroll") for (int m_ = 0; m_ < 4; ++m_) \
    _Pragma("unroll") for (int n_ = 0; n_ < 2; ++n_) \
    _Pragma("unroll") for (int ks_ = 0; ks_ < 2; ++ks_) \
        acc[(MB) + m_][(NB) + n_] = __builtin_amdgcn_mfma_f32_16x16x32_f16( \
            a[m_ * 2 + ks_], BARR[n_ * 2 + ks_], acc[(MB) + m_][(NB) + n_], 0, 0, 0); \
    __builtin_amdgcn_s_setprio(0);

// ph type A: 12 reads (a m0-3, bl n0-1), MFMA acc[0-3][0-1]; NO closing barrier
#define PH_A(s, STAGE) \
    _Pragma("unroll") for (int m_ = 0; m_ < 4; ++m_) { a[m_*2] = FA(s, m_, 0); a[m_*2+1] = FA(s, m_, 1); } \
    _Pragma("unroll") for (int n_ = 0; n_ < 2; ++n_) { bl[n_*2] = FB(s, n_, 0); bl[n_*2+1] = FB(s, n_, 1); } \
    STAGE; SBARx(); BARx(); LGKM0(); SBARx(); MFMA16(0, 0, bl)
// ph type B: 4 reads (bh n2-3), MFMA acc[0-3][2-3]; NO closing barrier
#define PH_B(s, STAGE) \
    _Pragma("unroll") for (int n_ = 0; n_ < 2; ++n_) { bh[n_*2] = FB(s, 2+n_, 0); bh[n_*2+1] = FB(s, 2+n_, 1); } \
    STAGE; SBARx(); BARx(); LGKM0(); SBARx(); MFMA16(0, 2, bh)
// ph type C: 8 reads (a m4-7), MFMA acc[4-7][0-1]; NO closing barrier
#define PH_C(s, STAGE) \
    _Pragma("unroll") for (int m_ = 0; m_ < 4; ++m_) { a[m_*2] = FA(s, 4+m_, 0); a[m_*2+1] = FA(s, 4+m_, 1); } \
    STAGE; SBARx(); BARx(); LGKM0(); SBARx(); MFMA16(4, 0, bl)
// ph type D: 0 reads, MFMA acc[4-7][2-3], counted vmcnt + CLOSING barrier (fence)
#define PH_D(s, STAGE, VMW) \
    STAGE; SBARx(); BARx(); LGKM0(); SBARx(); MFMA16(4, 2, bh) \
    asm volatile("s_waitcnt vmcnt(" VMW ")" ::: "memory"); BARx();

    // prologue: tile0 complete + tile1 B halves = 12 insts; vmcnt(4) => tile0 landed
    STG_A(0, 0, 0); STG_A(0, 1, 0); STG_B(0, 0, 0); STG_B(0, 1, 0);
    STG_B(1, 0, 1); STG_B(1, 1, 1);
    asm volatile("s_waitcnt vmcnt(4)" ::: "memory");
    BARx();

    // steady state: iter i processes K-tiles 2i (slot0), 2i+1 (slot1).
    // ph1:A0(2i+1) ph2:A1(2i+1) ph3:B0(2i+2) ph4:B1(2i+2)+vmcnt(4)+BAR
    // ph5:A0(2i+2) ph6:A1(2i+2) ph7:B0(2i+3) ph8:B1(2i+3)+vmcnt(4)+BAR
    for (int i = 0; i < 7; ++i) {
        const int k1 = 2 * i + 1, k2 = 2 * i + 2, k3 = 2 * i + 3;
        PH_A(0, STG_A(k1, 0, 1))
        PH_B(0, STG_A(k1, 1, 1))
        PH_C(0, STG_B(k2, 0, 0))
        PH_D(0, STG_B(k2, 1, 0), "4")
        PH_A(1, STG_A(k2, 0, 0))
        PH_B(1, STG_A(k2, 1, 0))
        PH_C(1, STG_B(k3, 0, 1))
        PH_D(1, STG_B(k3, 1, 1), "4")
    }
    // last iter: tiles 14,15; only tile-15 A halves remain to stage
    PH_A(0, STG_A(15, 0, 1))
    PH_B(0, STG_A(15, 1, 1))
    PH_C(0, ((void)0))
    PH_D(0, ((void)0), "0")
    PH_A(1, ((void)0))
    PH_B(1, ((void)0))
    PH_C(1, ((void)0))
    // tail ph8: no stage, no vmcnt needed
    SBARx(); BARx(); LGKM0(); SBARx(); MFMA16(4, 2, bh)

#undef PH_A
#undef PH_B
#undef PH_C
#undef PH_D
#undef MFMA16
#undef FA
#undef FB
#undef STG_A
#undef STG_B

    // ---- fused epilogue: part[row] = sum_cols tanh(acc+q)*omega (this wave's 64 cols)
    float part[8][4];
    #pragma unroll
    for (int m = 0; m < 8; ++m)
        #pragma unroll
        for (int r = 0; r < 4; ++r) part[m][r] = 0.f;

    #pragma unroll
    for (int n = 0; n < 4; ++n) {
        int col = col0 + wn * 64 + n * 16 + c15;
        float qv = q[b * DD + col];
        float om = omega[col];
        #pragma unroll
        for (int m = 0; m < 8; ++m)
            #pragma unroll
            for (int r = 0; r < 4; ++r)
                part[m][r] += ftanh(acc[m][n][r] + qv) * om;
    }

    __syncthreads();   // all waves done with LDS reads before As is reused
    float (*red)[4] = (float(*)[4])&As[0][0][0][0];   // [256][4] = 4 KB, As is dead
    #pragma unroll
    for (int m = 0; m < 8; ++m)
        #pragma unroll
        for (int r = 0; r < 4; ++r) {
            float s = part[m][r];
            s += __shfl_xor(s, 1, 64);
            s += __shfl_xor(s, 2, 64);
            s += __shfl_xor(s, 4, 64);
            s += __shfl_xor(s, 8, 64);
            if (c15 == 0) red[wm * 128 + m * 16 + quad * 4 + r][wn] = s;
        }
    __syncthreads();
    if (tid < 256)
        sig_part[(size_t)colBlk * MM + row0 + tid] =
            red[tid][0] + red[tid][1] + red[tid][2] + red[tid][3];
}

// ---------------- K3: per-b softmax-style weights (64 blocks: 8 per b)
__global__ __launch_bounds__(256) void softmax_k(const float* __restrict__ sig_part,
                                                 const float* __restrict__ imp,
                                                 float* __restrict__ a_ij) {
    int b = blockIdx.x >> 3, slice = blockIdx.x & 7;
    int tid = threadIdx.x;
    __shared__ float red[256];
    float sv[8];
    float m = -1e30f;
    #pragma unroll
    for (int p = 0; p < 8; ++p) {
        int n = p * 256 + tid;
        float s = 0.f;
        #pragma unroll
        for (int db = 0; db < 4; ++db) s += sig_part[db * MM + b * NN + n];
        sv[p] = s;
        m = fmaxf(m, s);
    }
    red[tid] = m; __syncthreads();
    for (int off = 128; off; off >>= 1) {
        if (tid < off) red[tid] = fmaxf(red[tid], red[tid + off]);
        __syncthreads();
    }
    m = red[0]; __syncthreads();
    float sum = 0.f;
    #pragma unroll
    for (int p = 0; p < 8; ++p) sum += expf(sv[p] - m);
    red[tid] = sum; __syncthreads();
    for (int off = 128; off; off >>= 1) {
        if (tid < off) red[tid] += red[tid + off];
        __syncthreads();
    }
    float inv = 1.f / (red[0] + 1e-9f * expf(-m));
    int n = slice * 256 + tid;
    a_ij[b * NN + n] = imp[b * NN + n] * expf(sv[slice] - m) * inv;
}

// ---------------- K4: u partials from fp16 e_j: 1024 blocks, disjoint writes
__global__ __launch_bounds__(256) void u_kernel(const float* __restrict__ a_ij,
                                                const _Float16* __restrict__ eh,
                                                float* __restrict__ u_part) {
    int b = blockIdx.x >> 7, nc = blockIdx.x & 127;
    int t = threadIdx.x;
    float4 acc = {0.f, 0.f, 0.f, 0.f};
    const _Float16* base = eh + ((size_t)(b * NN + nc * 16)) * DD + t * 4;
    const float* ap = a_ij + b * NN + nc * 16;
    #pragma unroll
    for (int n = 0; n < 16; ++n) {
        float a = ap[n];
        half4 v = *(const half4*)(base + (size_t)n * DD);
        acc.x += a * (float)v[0]; acc.y += a * (float)v[1];
        acc.z += a * (float)v[2]; acc.w += a * (float)v[3];
    }
    *(float4*)(u_part + ((size_t)nc * BB + b) * DD + t * 4) = acc;
}

// ---------------- K5: u[b,e] = sum over 128 partials
__global__ __launch_bounds__(256) void ureduce(const float* __restrict__ u_part,
                                               float* __restrict__ u) {
    int i = blockIdx.x * 256 + threadIdx.x;   // < 8192
    float s = 0.f;
    #pragma unroll 8
    for (int nc = 0; nc < 128; ++nc) s += u_part[(size_t)nc * BB * DD + i];
    u[i] = s;
}

// ---------------- K6: A = X @ W^T with X cached in LDS; W read once (256 blocks)
__global__ __launch_bounds__(256) void rowdot8(const float* __restrict__ X,
                                               const float* __restrict__ W,
                                               float* __restrict__ out) {
    __shared__ float us[BB][DD];
    int tid = threadIdx.x;
    for (int i = tid; i < BB * DD / 4; i += 256)
        ((float4*)&us[0][0])[i] = ((const float4*)X)[i];
    __syncthreads();
    int w = tid >> 6, lane = tid & 63;
    int d = blockIdx.x * 4 + w;
    float acc[8] = {0.f, 0.f, 0.f, 0.f, 0.f, 0.f, 0.f, 0.f};
    for (int e0 = 0; e0 < DD; e0 += 256) {
        float4 wv = *(const float4*)&W[(size_t)d * DD + e0 + lane * 4];
        #pragma unroll
        for (int r = 0; r < 8; ++r) {
            float4 uv = *(const float4*)&us[r][e0 + lane * 4];
            acc[r] += wv.x * uv.x + wv.y * uv.y + wv.z * uv.z + wv.w * uv.w;
        }
    }
    #pragma unroll
    for (int r = 0; r < 8; ++r) {
        float s = acc[r];
        #pragma unroll
        for (int off = 32; off; off >>= 1) s += __shfl_down(s, off, 64);
        if (lane == 0) out[r * DD + d] = s;
    }
}

// ---------------- K7: outputs: A, A_lk = A*R, A_l = A
__global__ __launch_bounds__(256) void out_kernel(const float* __restrict__ A,
                                                  const float* __restrict__ Rlk,
                                                  float* __restrict__ out) {
    int i = blockIdx.x * 256 + threadIdx.x;
    int d = i & (DD - 1);
    int l = (i >> 10) & (LL - 1);
    int b = i >> 17;
    out[BB * DD + i] = A[b * DD + d] * Rlk[l * DD + d];
    if (i < BB * DD) {
        out[i] = A[i];
        out[BB * DD + BB * LL * DD + i] = A[i];
    }
}

extern "C" void kernel_launch(void* const* d_in, const int* in_sizes, int n_in,
                              void* d_out, int out_size, void* d_ws, size_t ws_size,
                              hipStream_t stream) {
    const float* e_i   = (const float*)d_in[0];
    const float* e_j   = (const float*)d_in[1];
    const float* imp   = (const float*)d_in[2];
    const float* Rlk   = (const float*)d_in[3];
    const float* Wq    = (const float*)d_in[4];
    const float* Wk    = (const float*)d_in[5];
    const float* Wv    = (const float*)d_in[6];
    const float* omega = (const float*)d_in[7];
    float* out = (float*)d_out;
    float* ws  = (float*)d_ws;

    float* q    = ws;               // 8192
    float* sigp = ws + 8192;        // 65536 used (region holds 131072)
    float* a_ij = ws + 139264;      // 16384 (head reused as Abuf)
    float* u    = ws + 155648;      // 8192
    _Float16* eh = (_Float16*)(ws + 172032);      // MM*DD halfs = 32 MB
    _Float16* wh = eh + (size_t)MM * DD;          // 2 MB
    float* u_part = (float*)(wh + (size_t)DD * DD);  // 4 MB

    // K1: e_j -> fp16, Wk -> fp16, q = e_i @ Wq^T (Wq read once)
    prep_kernel<<<8960, 256, 0, stream>>>(e_j, eh, Wk, wh, e_i, Wq, q);

    // K2: sigma partials: 8-phase skeleton, open-barrier phases + ph4/ph8 fences
    sigma256<<<dim3(256), 512, 0, stream>>>(eh, wh, q, omega, sigp);

    // K3: a_ij
    softmax_k<<<64, 256, 0, stream>>>(sigp, imp, a_ij);

    // K4/K5: u partials (no atomics) from fp16 e_j, then reduce
    u_kernel<<<1024, 256, 0, stream>>>(a_ij, eh, u_part);
    ureduce<<<32, 256, 0, stream>>>(u_part, u);

    // K6: A = u @ Wv^T (Wv read once; Abuf = a_ij head)
    rowdot8<<<256, 256, 0, stream>>>(u, Wv, a_ij);

    // K7: outputs
    out_kernel<<<(BB * LL * DD) / 256, 256, 0, stream>>>(a_ij, Rlk, out);
}

// Round 8
// 182.604 us; speedup vs baseline: 1.1751x; 1.0186x over previous
//
#include <hip/hip_runtime.h>
#include <hip/hip_bf16.h>
#include <math.h>

#define BB 8
#define NN 2048
#define DD 1024
#define LL 128
#define MM (BB*NN)   // 16384

typedef _Float16 half8 __attribute__((ext_vector_type(8)));
typedef _Float16 half4 __attribute__((ext_vector_type(4)));
typedef __attribute__((ext_vector_type(4))) float floatx4;

__device__ __forceinline__ void glds16(const void* g, void* l) {
    __builtin_amdgcn_global_load_lds(
        (const __attribute__((address_space(1))) unsigned int*)g,
        (__attribute__((address_space(3))) unsigned int*)l, 16, 0, 0);
}

// fast tanh: 1 - 2/(e^{2x}+1); saturates correctly for |x| large, ~1e-6 abs err
__device__ __forceinline__ float ftanh(float x) {
    float e = __expf(2.0f * x);
    return 1.0f - 2.0f * __builtin_amdgcn_rcpf(e + 1.0f);
}

// ---------------- K1: e_j -> fp16, Wk -> fp16, q = e_i @ Wq^T
__global__ __launch_bounds__(256) void prep_kernel(const float* __restrict__ e_j,
                                                   _Float16* __restrict__ eh,
                                                   const float* __restrict__ Wk,
                                                   _Float16* __restrict__ wh,
                                                   const float* __restrict__ e_i,
                                                   const float* __restrict__ Wq,
                                                   float* __restrict__ q) {
    __shared__ float us[BB][DD];   // 32 KB, used only by the q branch
    int blk = blockIdx.x;
    int tid = threadIdx.x;
    if (blk < 8192) {
        int i = blk * 256 + tid;
        const float4* xp = (const float4*)e_j + (size_t)i * 2;
        float4 v0 = xp[0], v1 = xp[1];
        half8 h;
        h[0] = (_Float16)v0.x; h[1] = (_Float16)v0.y;
        h[2] = (_Float16)v0.z; h[3] = (_Float16)v0.w;
        h[4] = (_Float16)v1.x; h[5] = (_Float16)v1.y;
        h[6] = (_Float16)v1.z; h[7] = (_Float16)v1.w;
        *(half8*)(eh + (size_t)i * 8) = h;
    } else if (blk < 8704) {
        int i = (blk - 8192) * 256 + tid;
        const float4* xp = (const float4*)Wk + (size_t)i * 2;
        float4 v0 = xp[0], v1 = xp[1];
        half8 h;
        h[0] = (_Float16)v0.x; h[1] = (_Float16)v0.y;
        h[2] = (_Float16)v0.z; h[3] = (_Float16)v0.w;
        h[4] = (_Float16)v1.x; h[5] = (_Float16)v1.y;
        h[6] = (_Float16)v1.z; h[7] = (_Float16)v1.w;
        *(half8*)(wh + (size_t)i * 8) = h;
    } else {
        for (int i = tid; i < BB * DD / 4; i += 256)
            ((float4*)&us[0][0])[i] = ((const float4*)e_i)[i];
        __syncthreads();
        int w = tid >> 6, lane = tid & 63;
        int d = (blk - 8704) * 4 + w;
        float acc[8] = {0.f, 0.f, 0.f, 0.f, 0.f, 0.f, 0.f, 0.f};
        for (int e0 = 0; e0 < DD; e0 += 256) {
            float4 wv = *(const float4*)&Wq[(size_t)d * DD + e0 + lane * 4];
            #pragma unroll
            for (int r = 0; r < 8; ++r) {
                float4 uv = *(const float4*)&us[r][e0 + lane * 4];
                acc[r] += wv.x * uv.x + wv.y * uv.y + wv.z * uv.z + wv.w * uv.w;
            }
        }
        #pragma unroll
        for (int r = 0; r < 8; ++r) {
            float s = acc[r];
            #pragma unroll
            for (int off = 32; off; off >>= 1) s += __shfl_down(s, off, 64);
            if (lane == 0) q[r * DD + d] = s;
        }
    }
}

// ---------------- K2: sigma. Merged 4-phase skeleton (from R7's 8-phase):
//  X1(s): 16 ds_reads (a0-3,bl,bh) | stage | bar | lgkm0 | 32 MFMA (acc[0-3][*])
//  X2(s):  8 ds_reads (a4-7)       | stage | bar | lgkm0 | 32 MFMA (acc[4-7][*]) | vmcnt | bar
// Halves sync events vs R7 (6 bars/iter vs 10) and doubles MFMA cluster length.
// Stage/vmcnt ledger per iter i (t0=2i->s0, t1=2i+1->s1, k2=2i+2, k3=2i+3):
//  X1(s0): A(t1->s1)   X2(s0): B(k2->s0), vmcnt(4) certifies A(t1)
//  X1(s1): A(k2->s0)   X2(s1): B(k3->s1), vmcnt(4) certifies A(k2)+B(k2)
// Overwrite safety: A-stages follow the fence barrier of the phase that last
// read the target; B-stages use the R7-validated {bar,lgkm0,MFMA,stage} gap.
__global__ __launch_bounds__(512, 2) void sigma256(const _Float16* __restrict__ eh,
                                                   const _Float16* __restrict__ wh,
                                                   const float* __restrict__ q,
                                                   const float* __restrict__ omega,
                                                   float* __restrict__ sig_part) // [4][MM]
{
    __shared__ _Float16 As[2][2][128][64];   // [slot][half] 64 KB
    __shared__ _Float16 Bs[2][2][128][64];   // 64 KB

    const int tid  = threadIdx.x;
    const int lane = tid & 63;
    const int wid  = tid >> 6;          // 0..7
    const int wm   = wid >> 2;          // 0..1 : A 128-row block
    const int wn   = wid & 3;           // 0..3 : 64-col block
    const int c15  = lane & 15, quad = lane >> 4;

    // XCD-chunked bijective swizzle: 256 wgs, 32 per XCD
    const int wgid   = (blockIdx.x & 7) * 32 + (blockIdx.x >> 3);
    const int colBlk = wgid >> 6;        // 0..3
    const int rowBlk = wgid & 63;        // 0..63
    const int row0   = rowBlk * 256;
    const int col0   = colBlk * 256;
    const int b      = row0 / NN;

    // staging: linear LDS dest, 8-way XOR swizzle folded into global source
    const int l3  = lane >> 3;
    const int qst = ((lane & 7) ^ l3) * 8;     // halfs
    const _Float16* gA = eh + (size_t)(row0 + wid * 16 + l3) * DD + qst;
    const _Float16* gB = wh + (size_t)(col0 + wid * 16 + l3) * DD + qst;
    char* const ldsA = (char*)&As[0][0][0][0] + wid * 2048;
    char* const ldsB = (char*)&Bs[0][0][0][0] + wid * 2048;

#define STG_A(kt, hf, s) do { \
    glds16(gA + (size_t)(hf) * 128 * DD + (kt) * 64,          ldsA + (s) * 32768 + (hf) * 16384); \
    glds16(gA + (size_t)(hf) * 128 * DD + (kt) * 64 + 8 * DD, ldsA + (s) * 32768 + (hf) * 16384 + 1024); } while (0)
#define STG_B(kt, hf, s) do { \
    glds16(gB + (size_t)(hf) * 128 * DD + (kt) * 64,          ldsB + (s) * 32768 + (hf) * 16384); \
    glds16(gB + (size_t)(hf) * 128 * DD + (kt) * 64 + 8 * DD, ldsB + (s) * 32768 + (hf) * 16384 + 1024); } while (0)
#define STG_A2(kt, s) do { STG_A(kt, 0, s); STG_A(kt, 1, s); } while (0)
#define STG_B2(kt, s) do { STG_B(kt, 0, s); STG_B(kt, 1, s); } while (0)

    // swizzled fragment reads: row stride 128B, q' = q ^ (row&7)
    const int swz = c15 & 7;
    const int q0  = (quad ^ swz) << 4;
    const int q1  = ((4 + quad) ^ swz) << 4;
    const char* const afp = (const char*)&As[0][0][0][0] + wm * 16384 + c15 * 128;
    const char* const bfp = (const char*)&Bs[0][0][0][0] + (wn >> 1) * 16384
                            + ((wn & 1) * 64 + c15) * 128;
#define FA(s, m, ks) (*(const half8*)(afp + (s) * 32768 + (m) * 2048 + ((ks) ? q1 : q0)))
#define FB(s, n, ks) (*(const half8*)(bfp + (s) * 32768 + (n) * 2048 + ((ks) ? q1 : q0)))

    floatx4 acc[8][4];
    #pragma unroll
    for (int m = 0; m < 8; ++m)
        #pragma unroll
        for (int n = 0; n < 4; ++n) acc[m][n] = (floatx4){0.f, 0.f, 0.f, 0.f};

    half8 a[8], bl[4], bh[4];

#define BARx()  __builtin_amdgcn_s_barrier()
#define SBARx() __builtin_amdgcn_sched_barrier(0)
#define LGKM0() asm volatile("s_waitcnt lgkmcnt(0)" ::: "memory")
#define NOPX ((void)0)

#define MFMA32(MB) \
    __builtin_amdgcn_s_setprio(1); \
    _Pragma("unroll") for (int m_ = 0; m_ < 4; ++m_) \
    _Pragma("unroll") for (int ks_ = 0; ks_ < 2; ++ks_) { \
        acc[(MB)+m_][0] = __builtin_amdgcn_mfma_f32_16x16x32_f16(a[m_*2+ks_], bl[ks_],     acc[(MB)+m_][0], 0, 0, 0); \
        acc[(MB)+m_][1] = __builtin_amdgcn_mfma_f32_16x16x32_f16(a[m_*2+ks_], bl[2+ks_],   acc[(MB)+m_][1], 0, 0, 0); \
        acc[(MB)+m_][2] = __builtin_amdgcn_mfma_f32_16x16x32_f16(a[m_*2+ks_], bh[ks_],     acc[(MB)+m_][2], 0, 0, 0); \
        acc[(MB)+m_][3] = __builtin_amdgcn_mfma_f32_16x16x32_f16(a[m_*2+ks_], bh[2+ks_],   acc[(MB)+m_][3], 0, 0, 0); \
    } \
    __builtin_amdgcn_s_setprio(0);

// X1: 16 reads (a0-3 both k-slots, bl, bh), stage, 32 MFMA on acc[0-3][0-3]
#define PH_X1(s, STAGE) \
    _Pragma("unroll") for (int m_ = 0; m_ < 4; ++m_) { a[m_*2] = FA(s, m_, 0); a[m_*2+1] = FA(s, m_, 1); } \
    _Pragma("unroll") for (int n_ = 0; n_ < 2; ++n_) { bl[n_*2] = FB(s, n_, 0);   bl[n_*2+1] = FB(s, n_, 1); } \
    _Pragma("unroll") for (int n_ = 0; n_ < 2; ++n_) { bh[n_*2] = FB(s, 2+n_, 0); bh[n_*2+1] = FB(s, 2+n_, 1); } \
    STAGE; SBARx(); BARx(); LGKM0(); SBARx(); MFMA32(0)
// X2: 8 reads (a4-7), stage, 32 MFMA on acc[4-7][0-3], counted vmcnt + fence bar
#define PH_X2(s, STAGE, VMW) \
    _Pragma("unroll") for (int m_ = 0; m_ < 4; ++m_) { a[m_*2] = FA(s, 4+m_, 0); a[m_*2+1] = FA(s, 4+m_, 1); } \
    STAGE; SBARx(); BARx(); LGKM0(); SBARx(); MFMA32(4) \
    asm volatile("s_waitcnt vmcnt(" VMW ")" ::: "memory"); BARx();

    // prologue: tile0 complete + tile1 B halves = 12 insts; vmcnt(4) => tile0 landed
    STG_A2(0, 0); STG_B2(0, 0);
    STG_B2(1, 1);
    asm volatile("s_waitcnt vmcnt(4)" ::: "memory");
    BARx();

    for (int i = 0; i < 7; ++i) {
        const int k1 = 2 * i + 1, k2 = 2 * i + 2, k3 = 2 * i + 3;
        PH_X1(0, STG_A2(k1, 1))
        PH_X2(0, STG_B2(k2, 0), "4")
        PH_X1(1, STG_A2(k2, 0))
        PH_X2(1, STG_B2(k3, 1), "4")
    }
    // tail iter: tiles 14,15; only tile-15 A halves remain to stage
    PH_X1(0, STG_A2(15, 1))
    PH_X2(0, NOPX, "0")
    PH_X1(1, NOPX)
    // final X2 (no stage, no fence)
    _Pragma("unroll") for (int m_ = 0; m_ < 4; ++m_) { a[m_*2] = FA(1, 4+m_, 0); a[m_*2+1] = FA(1, 4+m_, 1); }
    SBARx(); BARx(); LGKM0(); SBARx(); MFMA32(4)

#undef PH_X1
#undef PH_X2
#undef MFMA32
#undef FA
#undef FB
#undef STG_A
#undef STG_B
#undef STG_A2
#undef STG_B2

    // ---- fused epilogue: part[row] = sum_cols tanh(acc+q)*omega (this wave's 64 cols)
    float part[8][4];
    #pragma unroll
    for (int m = 0; m < 8; ++m)
        #pragma unroll
        for (int r = 0; r < 4; ++r) part[m][r] = 0.f;

    #pragma unroll
    for (int n = 0; n < 4; ++n) {
        int col = col0 + wn * 64 + n * 16 + c15;
        float qv = q[b * DD + col];
        float om = omega[col];
        #pragma unroll
        for (int m = 0; m < 8; ++m)
            #pragma unroll
            for (int r = 0; r < 4; ++r)
                part[m][r] += ftanh(acc[m][n][r] + qv) * om;
    }

    __syncthreads();   // all waves done with LDS reads before As is reused
    float (*red)[4] = (float(*)[4])&As[0][0][0][0];   // [256][4] = 4 KB, As is dead
    #pragma unroll
    for (int m = 0; m < 8; ++m)
        #pragma unroll
        for (int r = 0; r < 4; ++r) {
            float s = part[m][r];
            s += __shfl_xor(s, 1, 64);
            s += __shfl_xor(s, 2, 64);
            s += __shfl_xor(s, 4, 64);
            s += __shfl_xor(s, 8, 64);
            if (c15 == 0) red[wm * 128 + m * 16 + quad * 4 + r][wn] = s;
        }
    __syncthreads();
    if (tid < 256)
        sig_part[(size_t)colBlk * MM + row0 + tid] =
            red[tid][0] + red[tid][1] + red[tid][2] + red[tid][3];
}

// ---------------- K3: per-b softmax-style weights (64 blocks: 8 per b)
__global__ __launch_bounds__(256) void softmax_k(const float* __restrict__ sig_part,
                                                 const float* __restrict__ imp,
                                                 float* __restrict__ a_ij) {
    int b = blockIdx.x >> 3, slice = blockIdx.x & 7;
    int tid = threadIdx.x;
    __shared__ float red[256];
    float sv[8];
    float m = -1e30f;
    #pragma unroll
    for (int p = 0; p < 8; ++p) {
        int n = p * 256 + tid;
        float s = 0.f;
        #pragma unroll
        for (int db = 0; db < 4; ++db) s += sig_part[db * MM + b * NN + n];
        sv[p] = s;
        m = fmaxf(m, s);
    }
    red[tid] = m; __syncthreads();
    for (int off = 128; off; off >>= 1) {
        if (tid < off) red[tid] = fmaxf(red[tid], red[tid + off]);
        __syncthreads();
    }
    m = red[0]; __syncthreads();
    float sum = 0.f;
    #pragma unroll
    for (int p = 0; p < 8; ++p) sum += expf(sv[p] - m);
    red[tid] = sum; __syncthreads();
    for (int off = 128; off; off >>= 1) {
        if (tid < off) red[tid] += red[tid + off];
        __syncthreads();
    }
    float inv = 1.f / (red[0] + 1e-9f * expf(-m));
    int n = slice * 256 + tid;
    a_ij[b * NN + n] = imp[b * NN + n] * expf(sv[slice] - m) * inv;
}

// ---------------- K4: u partials from fp16 e_j: 1024 blocks, disjoint writes
__global__ __launch_bounds__(256) void u_kernel(const float* __restrict__ a_ij,
                                                const _Float16* __restrict__ eh,
                                                float* __restrict__ u_part) {
    int b = blockIdx.x >> 7, nc = blockIdx.x & 127;
    int t = threadIdx.x;
    float4 acc = {0.f, 0.f, 0.f, 0.f};
    const _Float16* base = eh + ((size_t)(b * NN + nc * 16)) * DD + t * 4;
    const float* ap = a_ij + b * NN + nc * 16;
    #pragma unroll
    for (int n = 0; n < 16; ++n) {
        float a = ap[n];
        half4 v = *(const half4*)(base + (size_t)n * DD);
        acc.x += a * (float)v[0]; acc.y += a * (float)v[1];
        acc.z += a * (float)v[2]; acc.w += a * (float)v[3];
    }
    *(float4*)(u_part + ((size_t)nc * BB + b) * DD + t * 4) = acc;
}

// ---------------- K5: u[b,e] = sum over 128 partials
__global__ __launch_bounds__(256) void ureduce(const float* __restrict__ u_part,
                                               float* __restrict__ u) {
    int i = blockIdx.x * 256 + threadIdx.x;   // < 8192
    float s = 0.f;
    #pragma unroll 8
    for (int nc = 0; nc < 128; ++nc) s += u_part[(size_t)nc * BB * DD + i];
    u[i] = s;
}

// ---------------- K6: A = X @ W^T with X cached in LDS; W read once (256 blocks)
__global__ __launch_bounds__(256) void rowdot8(const float* __restrict__ X,
                                               const float* __restrict__ W,
                                               float* __restrict__ out) {
    __shared__ float us[BB][DD];
    int tid = threadIdx.x;
    for (int i = tid; i < BB * DD / 4; i += 256)
        ((float4*)&us[0][0])[i] = ((const float4*)X)[i];
    __syncthreads();
    int w = tid >> 6, lane = tid & 63;
    int d = blockIdx.x * 4 + w;
    float acc[8] = {0.f, 0.f, 0.f, 0.f, 0.f, 0.f, 0.f, 0.f};
    for (int e0 = 0; e0 < DD; e0 += 256) {
        float4 wv = *(const float4*)&W[(size_t)d * DD + e0 + lane * 4];
        #pragma unroll
        for (int r = 0; r < 8; ++r) {
            float4 uv = *(const float4*)&us[r][e0 + lane * 4];
            acc[r] += wv.x * uv.x + wv.y * uv.y + wv.z * uv.z + wv.w * uv.w;
        }
    }
    #pragma unroll
    for (int r = 0; r < 8; ++r) {
        float s = acc[r];
        #pragma unroll
        for (int off = 32; off; off >>= 1) s += __shfl_down(s, off, 64);
        if (lane == 0) out[r * DD + d] = s;
    }
}

// ---------------- K7: outputs: A, A_lk = A*R, A_l = A
__global__ __launch_bounds__(256) void out_kernel(const float* __restrict__ A,
                                                  const float* __restrict__ Rlk,
                                                  float* __restrict__ out) {
    int i = blockIdx.x * 256 + threadIdx.x;
    int d = i & (DD - 1);
    int l = (i >> 10) & (LL - 1);
    int b = i >> 17;
    out[BB * DD + i] = A[b * DD + d] * Rlk[l * DD + d];
    if (i < BB * DD) {
        out[i] = A[i];
        out[BB * DD + BB * LL * DD + i] = A[i];
    }
}

extern "C" void kernel_launch(void* const* d_in, const int* in_sizes, int n_in,
                              void* d_out, int out_size, void* d_ws, size_t ws_size,
                              hipStream_t stream) {
    const float* e_i   = (const float*)d_in[0];
    const float* e_j   = (const float*)d_in[1];
    const float* imp   = (const float*)d_in[2];
    const float* Rlk   = (const float*)d_in[3];
    const float* Wq    = (const float*)d_in[4];
    const float* Wk    = (const float*)d_in[5];
    const float* Wv    = (const float*)d_in[6];
    const float* omega = (const float*)d_in[7];
    float* out = (float*)d_out;
    float* ws  = (float*)d_ws;

    float* q    = ws;               // 8192
    float* sigp = ws + 8192;        // 65536 used (region holds 131072)
    float* a_ij = ws + 139264;      // 16384 (head reused as Abuf)
    float* u    = ws + 155648;      // 8192
    _Float16* eh = (_Float16*)(ws + 172032);      // MM*DD halfs = 32 MB
    _Float16* wh = eh + (size_t)MM * DD;          // 2 MB
    float* u_part = (float*)(wh + (size_t)DD * DD);  // 4 MB

    // K1: e_j -> fp16, Wk -> fp16, q = e_i @ Wq^T (Wq read once)
    prep_kernel<<<8960, 256, 0, stream>>>(e_j, eh, Wk, wh, e_i, Wq, q);

    // K2: sigma partials: merged 4-phase pipeline (32-MFMA clusters)
    sigma256<<<dim3(256), 512, 0, stream>>>(eh, wh, q, omega, sigp);

    // K3: a_ij
    softmax_k<<<64, 256, 0, stream>>>(sigp, imp, a_ij);

    // K4/K5: u partials (no atomics) from fp16 e_j, then reduce
    u_kernel<<<1024, 256, 0, stream>>>(a_ij, eh, u_part);
    ureduce<<<32, 256, 0, stream>>>(u_part, u);

    // K6: A = u @ Wv^T (Wv read once; Abuf = a_ij head)
    rowdot8<<<256, 256, 0, stream>>>(u, Wv, a_ij);

    // K7: outputs
    out_kernel<<<(BB * LL * DD) / 256, 256, 0, stream>>>(a_ij, Rlk, out);
}